// Round 4
// baseline (470.187 us; speedup 1.0000x reference)
//
#include <hip/hip_runtime.h>
#include <hip/hip_bf16.h>
#include <stdint.h>

typedef __attribute__((ext_vector_type(8))) short bh8;
typedef __attribute__((ext_vector_type(4))) float f32x4;
typedef unsigned short u16;
typedef unsigned int u32;

#define B_    8
#define C_    512
#define LF    16384
#define KTOT  1536
#define FTR   (LF + 2)      // padded rows per half-batch entry
#define BM    128
#define BN    128
#define LDT   72            // ushorts per row of As/Bs (64 + 8 pad)

// ws layout (bytes), per-half double-use:
#define FT_OFF   0
#define FT_HALF_BYTES  ((size_t)4 * FTR * C_ * 2)   // 67,117,056
#define H_OFF    FT_HALF_BYTES
#define H_HALF_BYTES   ((size_t)4 * C_ * LF * 2)    // 67,108,864
#define W2_OFF   (H_OFF + H_HALF_BYTES)             // +1,572,864 => ~136 MB

// output chunk offsets (FLOAT32 elements)
#define OBJ_OFF  0
#define REG_OFF  917504      // 8 * 16384*7
#define ANC_OFF  2752512     // REG_OFF + 8*16384*14

__device__ __forceinline__ u16 f2bf(float f) {
    u32 u = __float_as_uint(f);
    return (u16)((u + 0x7FFFu + ((u >> 16) & 1u)) >> 16);
}
__device__ __forceinline__ float bf2f(u16 h) {
    return __uint_as_float(((u32)h) << 16);
}

// ---------------- cast conv_w -> W2[co][t*512+ci] (t-major K) ----------------
__global__ void k_cast_w(const float* __restrict__ cw, u16* __restrict__ W2) {
    int i = blockIdx.x * 256 + threadIdx.x;
    if (i >= C_ * KTOT) return;
    int co = i / KTOT, r = i % KTOT;
    int t = r >> 9, ci = r & 511;
    W2[i] = f2bf(cw[(co * C_ + ci) * 3 + t]);
}

// ---------------- anchors (float32 out) ----------------
__global__ void k_anchors(float* __restrict__ out) {
    int l = blockIdx.x * 256 + threadIdx.x;
    if (l >= LF) return;
    const float AL[7] = {1.f, 2.f, 3.f, 4.f, 5.f, 7.f, 9.f};
    float c = (float)l + 0.5f;
    float* an = out + ANC_OFF + (size_t)l * 14;
#pragma unroll
    for (int a = 0; a < 7; ++a) {
        an[a * 2 + 0] = c - 0.5f * AL[a];
        an[a * 2 + 1] = c + 0.5f * AL[a];
    }
}

// ---------------- zero FT pad rows (l = -1 and l = Lf) for 4 batches ----------------
__global__ void k_zero_pad(u16* __restrict__ FT) {
    int i = blockIdx.x * 256 + threadIdx.x;   // 4*2*512 = 4096
    if (i >= 4 * 2 * C_) return;
    int b = i >> 10, r = (i >> 9) & 1, c = i & 511;
    size_t row = r ? (size_t)(LF + 1) : 0;
    FT[((size_t)b * FTR + row) * C_ + c] = 0;
}

// ---------------- tiled transpose: feat(b0+4,C,Lf) f32 -> FT(4, Lf+2, C) bf16 ----------------
__global__ __launch_bounds__(256) void k_transpose(const float* __restrict__ feat,
                                                   u16* __restrict__ FT, int b0) {
    __shared__ float Tt[64][33];
    const int b = blockIdx.z, c0 = blockIdx.y * 32, l0 = blockIdx.x * 64;
    const int tx = threadIdx.x & 15, cy = threadIdx.x >> 4;   // cy 0..15
#pragma unroll
    for (int it = 0; it < 2; ++it) {
        int c = cy + it * 16;
        float4 v = *(const float4*)(feat +
            ((size_t)((b0 + b) * C_ + c0 + c) * LF + l0 + tx * 4));
        Tt[tx * 4 + 0][c] = v.x;
        Tt[tx * 4 + 1][c] = v.y;
        Tt[tx * 4 + 2][c] = v.z;
        Tt[tx * 4 + 3][c] = v.w;
    }
    __syncthreads();
    const int c4 = (threadIdx.x & 7) * 4, lr0 = threadIdx.x >> 3;  // lr0 0..31
#pragma unroll
    for (int it = 0; it < 2; ++it) {
        int lr = lr0 + it * 32;
        uint2 o;
        o.x = (u32)f2bf(Tt[lr][c4 + 0]) | ((u32)f2bf(Tt[lr][c4 + 1]) << 16);
        o.y = (u32)f2bf(Tt[lr][c4 + 2]) | ((u32)f2bf(Tt[lr][c4 + 3]) << 16);
        *(uint2*)(FT + ((size_t)b * FTR + (l0 + lr + 1)) * C_ + c0 + c4) = o;
    }
}

// ---------------- conv GEMM -> relu -> H[b][co][l] bf16 ----------------
// grid: (Lf/128=128, C/128=4, 4), 256 threads (4 waves, 2x2)
__global__ __launch_bounds__(256, 2) void k_conv(
    const u16* __restrict__ FT, const u16* __restrict__ W2,
    const float* __restrict__ conv_b, u16* __restrict__ H) {
    __shared__ __align__(16) char smem[37376];
    u16* As = (u16*)smem;                  // [128][72]
    u16* Bs = (u16*)(smem + 18432);        // [128][72]
    float* cb = (float*)(smem + 36864);    // [128]

    const int tid = threadIdx.x;
    const int lane = tid & 63, wave = tid >> 6;
    const int wm = wave >> 1, wn = wave & 1;
    const int g = lane >> 4, cL = lane & 15;
    const int l0 = blockIdx.x * BN;
    const int co0 = blockIdx.y * BM;
    const int b = blockIdx.z;              // half-relative

    if (tid < BM) cb[tid] = conv_b[co0 + tid];

    f32x4 acc[4][4];
#pragma unroll
    for (int m = 0; m < 4; ++m)
#pragma unroll
        for (int n = 0; n < 4; ++n) acc[m][n] = {0.f, 0.f, 0.f, 0.f};

    const size_t ftbase = (size_t)b * FTR * C_;

    for (int ks = 0; ks < 24; ++ks) {
        const int t = ks >> 3, kc = (ks & 7) * 64;
        __syncthreads();
#pragma unroll
        for (int i = 0; i < 4; ++i) {
            int flat = i * 256 + tid;
            int row = flat >> 3, ch = (flat & 7) * 8;
            *(uint4*)&As[row * LDT + ch] =
                *(const uint4*)&W2[(size_t)(co0 + row) * KTOT + t * 512 + kc + ch];
            *(uint4*)&Bs[row * LDT + ch] =
                *(const uint4*)&FT[ftbase + (size_t)(l0 + t + row) * C_ + kc + ch];
        }
        __syncthreads();
#pragma unroll
        for (int kk = 0; kk < 2; ++kk) {
            const int ko = kk * 32 + g * 8;
            bh8 af[4], bfr[4];
#pragma unroll
            for (int m = 0; m < 4; ++m)
                af[m] = *(const bh8*)&As[(wm * 64 + m * 16 + cL) * LDT + ko];
#pragma unroll
            for (int n = 0; n < 4; ++n)
                bfr[n] = *(const bh8*)&Bs[(wn * 64 + n * 16 + cL) * LDT + ko];
#pragma unroll
            for (int m = 0; m < 4; ++m)
#pragma unroll
                for (int n = 0; n < 4; ++n)
                    acc[m][n] = __builtin_amdgcn_mfma_f32_16x16x32_bf16(af[m], bfr[n],
                                                                        acc[m][n], 0, 0, 0);
        }
    }

    // epilogue: bias + relu -> H[b][co][l] bf16 (global)
    u16* Hb = H + (size_t)b * C_ * LF;
#pragma unroll
    for (int m = 0; m < 4; ++m) {
        const int coB = wm * 64 + m * 16 + g * 4;     // block-relative co base
        const float b0_ = cb[coB + 0], b1_ = cb[coB + 1];
        const float b2_ = cb[coB + 2], b3_ = cb[coB + 3];
#pragma unroll
        for (int n = 0; n < 4; ++n) {
            const int l = l0 + wn * 64 + n * 16 + cL;
            f32x4 v = acc[m][n];
            Hb[(size_t)(co0 + coB + 0) * LF + l] = f2bf(fmaxf(v[0] + b0_, 0.f));
            Hb[(size_t)(co0 + coB + 1) * LF + l] = f2bf(fmaxf(v[1] + b1_, 0.f));
            Hb[(size_t)(co0 + coB + 2) * LF + l] = f2bf(fmaxf(v[2] + b2_, 0.f));
            Hb[(size_t)(co0 + coB + 3) * LF + l] = f2bf(fmaxf(v[3] + b3_, 0.f));
        }
    }
}

// ---------------- head: plain VALU dot products, writes obj+reg (float32) ----------------
// grid: (LF/256=64, 4), 256 threads; thread owns one l
__global__ __launch_bounds__(256) void k_head(
    const u16* __restrict__ H, const float* __restrict__ obj_w,
    const float* __restrict__ obj_b, const float* __restrict__ reg_w,
    const float* __restrict__ reg_b, float* __restrict__ out, int b0) {
    __shared__ float Wl[21 * 512];
    const int tid = threadIdx.x;
    for (int i = tid; i < 21 * 512; i += 256)
        Wl[i] = (i < 7 * 512) ? obj_w[i] : reg_w[i - 7 * 512];
    __syncthreads();

    const int l = blockIdx.x * 256 + tid;
    const int br = blockIdx.y;             // 0..3 half-relative
    const u16* Hp = H + (size_t)br * C_ * LF + l;

    float s[21];
#pragma unroll
    for (int a = 0; a < 21; ++a) s[a] = 0.f;
    for (int c = 0; c < C_; ++c) {
        float hv = bf2f(Hp[(size_t)c * LF]);
#pragma unroll
        for (int a = 0; a < 21; ++a) s[a] = fmaf(hv, Wl[a * 512 + c], s[a]);
    }

    const int bb = b0 + br;
    float* op = out + OBJ_OFF + (size_t)bb * (LF * 7) + (size_t)l * 7;
#pragma unroll
    for (int a = 0; a < 7; ++a) op[a] = s[a] + obj_b[a];
    float* rp = out + REG_OFF + (size_t)bb * (LF * 14) + (size_t)l * 14;
#pragma unroll
    for (int o = 0; o < 14; ++o) rp[o] = s[7 + o] + reg_b[o];
}

extern "C" void kernel_launch(void* const* d_in, const int* in_sizes, int n_in,
                              void* d_out, int out_size, void* d_ws, size_t ws_size,
                              hipStream_t stream) {
    const float* feat   = (const float*)d_in[0];
    const float* conv_w = (const float*)d_in[1];
    const float* conv_b = (const float*)d_in[2];
    const float* obj_w  = (const float*)d_in[3];
    const float* obj_b  = (const float*)d_in[4];
    const float* reg_w  = (const float*)d_in[5];
    const float* reg_b  = (const float*)d_in[6];
    char* ws = (char*)d_ws;
    u16* FT = (u16*)(ws + FT_OFF);
    u16* H  = (u16*)(ws + H_OFF);
    u16* W2 = (u16*)(ws + W2_OFF);
    float* out = (float*)d_out;

    k_cast_w<<<(C_ * KTOT + 255) / 256, 256, 0, stream>>>(conv_w, W2);
    k_anchors<<<LF / 256, 256, 0, stream>>>(out);

    for (int h = 0; h < 2; ++h) {
        const int b0 = h * 4;
        k_zero_pad<<<16, 256, 0, stream>>>(FT);
        dim3 gt(LF / 64, C_ / 32, 4);
        k_transpose<<<gt, 256, 0, stream>>>(feat, FT, b0);
        dim3 gc(LF / BN, C_ / BM, 4);
        k_conv<<<gc, 256, 0, stream>>>(FT, W2, conv_b, H);
        dim3 gh(LF / 256, 4);
        k_head<<<gh, 256, 0, stream>>>(H, obj_w, obj_b, reg_w, reg_b, out, b0);
    }
}

// Round 5
// 357.144 us; speedup vs baseline: 1.3165x; 1.3165x over previous
//
#include <hip/hip_runtime.h>
#include <hip/hip_bf16.h>
#include <stdint.h>

typedef __attribute__((ext_vector_type(8))) short bh8;
typedef __attribute__((ext_vector_type(4))) float f32x4;
typedef unsigned short u16;
typedef unsigned int u32;

#define B_    8
#define C_    512
#define LF    16384
#define KTOT  1536
#define FTR   (LF + 2)      // padded rows per half-batch entry
#define BM    128
#define BN    128
#define HSLD  136           // ushorts per row of Hs/Wp (128 + 8 pad)

// ws layout (bytes)
#define FT_OFF   0
#define FT_HALF_BYTES  ((size_t)4 * FTR * C_ * 2)    // 67,117,056
#define P4_OFF   FT_HALF_BYTES
#define P4_BYTES ((size_t)4 * B_ * 21 * LF * 4)      // 44,040,192
#define W2_OFF   (P4_OFF + P4_BYTES)                 // ~113 MB total

// output chunk offsets (float32 elements)
#define OBJ_OFF  0
#define REG_OFF  917504      // 8 * 16384*7
#define ANC_OFF  2752512     // REG_OFF + 8*16384*14

__device__ __forceinline__ u16 f2bf(float f) {
    u32 u = __float_as_uint(f);
    return (u16)((u + 0x7FFFu + ((u >> 16) & 1u)) >> 16);
}

__device__ __forceinline__ void gload16(const u16* g, u16* l) {
    __builtin_amdgcn_global_load_lds(
        (const __attribute__((address_space(1))) void*)g,
        (__attribute__((address_space(3))) void*)l, 16, 0, 0);
}

// ---------------- cast conv_w -> W2[co][t*512+ci] (t-major K) ----------------
__global__ void k_cast_w(const float* __restrict__ cw, u16* __restrict__ W2) {
    int i = blockIdx.x * 256 + threadIdx.x;
    if (i >= C_ * KTOT) return;
    int co = i / KTOT, r = i % KTOT;
    int t = r >> 9, ci = r & 511;
    W2[i] = f2bf(cw[(co * C_ + ci) * 3 + t]);
}

// ---------------- anchors (float32 out) ----------------
__global__ void k_anchors(float* __restrict__ out) {
    int l = blockIdx.x * 256 + threadIdx.x;
    if (l >= LF) return;
    const float AL[7] = {1.f, 2.f, 3.f, 4.f, 5.f, 7.f, 9.f};
    float c = (float)l + 0.5f;
    float* an = out + ANC_OFF + (size_t)l * 14;
#pragma unroll
    for (int a = 0; a < 7; ++a) {
        an[a * 2 + 0] = c - 0.5f * AL[a];
        an[a * 2 + 1] = c + 0.5f * AL[a];
    }
}

// ---------------- zero FT pad rows (l = -1 and l = Lf) for 4 batches ----------------
__global__ void k_zero_pad(u16* __restrict__ FT) {
    int i = blockIdx.x * 256 + threadIdx.x;   // 4*2*512 = 4096
    if (i >= 4 * 2 * C_) return;
    int b = i >> 10, r = (i >> 9) & 1, c = i & 511;
    size_t row = r ? (size_t)(LF + 1) : 0;
    FT[((size_t)b * FTR + row) * C_ + c] = 0;
}

// ---------------- tiled transpose: feat(b0+4,C,Lf) f32 -> FT(4, Lf+2, C) bf16 ----------------
__global__ __launch_bounds__(256) void k_transpose(const float* __restrict__ feat,
                                                   u16* __restrict__ FT, int b0) {
    __shared__ float Tt[64][33];
    const int b = blockIdx.z, c0 = blockIdx.y * 32, l0 = blockIdx.x * 64;
    const int tx = threadIdx.x & 15, cy = threadIdx.x >> 4;   // cy 0..15
#pragma unroll
    for (int it = 0; it < 2; ++it) {
        int c = cy + it * 16;
        float4 v = *(const float4*)(feat +
            ((size_t)((b0 + b) * C_ + c0 + c) * LF + l0 + tx * 4));
        Tt[tx * 4 + 0][c] = v.x;
        Tt[tx * 4 + 1][c] = v.y;
        Tt[tx * 4 + 2][c] = v.z;
        Tt[tx * 4 + 3][c] = v.w;
    }
    __syncthreads();
    const int c4 = (threadIdx.x & 7) * 4, lr0 = threadIdx.x >> 3;  // lr0 0..31
#pragma unroll
    for (int it = 0; it < 2; ++it) {
        int lr = lr0 + it * 32;
        uint2 o;
        o.x = (u32)f2bf(Tt[lr][c4 + 0]) | ((u32)f2bf(Tt[lr][c4 + 1]) << 16);
        o.y = (u32)f2bf(Tt[lr][c4 + 2]) | ((u32)f2bf(Tt[lr][c4 + 3]) << 16);
        *(uint2*)(FT + ((size_t)b * FTR + (l0 + lr + 1)) * C_ + c0 + c4) = o;
    }
}

// ---------------- conv GEMM (global_load_lds staging) + fused head ----------------
// grid: (Lf/128=128, C/128=4, 4), 256 threads (4 waves, 2x2)
__global__ __launch_bounds__(256, 2) void k_conv_head(
    const u16* __restrict__ FT, const u16* __restrict__ W2,
    const float* __restrict__ conv_b, const float* __restrict__ obj_w,
    const float* __restrict__ reg_w, float* __restrict__ P4, int b0) {
    __shared__ __align__(16) char smem[44032];
    u16* As = (u16*)smem;                  // [128][64] linear (gload dest)
    u16* Bs = (u16*)(smem + 16384);        // [128][64] linear
    u16* Hs = (u16*)smem;                  // [128][136] epilogue (overlaps As/Bs)
    u16* Wp = (u16*)(smem + 34816);        // [32][136]  epilogue
    float* cb = (float*)(smem + 43520);    // [128]

    const int tid = threadIdx.x;
    const int lane = tid & 63, wave = tid >> 6;
    const int wm = wave >> 1, wn = wave & 1;
    const int g = lane >> 4, cL = lane & 15;
    const int l0 = blockIdx.x * BN;
    const int mt = blockIdx.y;
    const int co0 = mt * BM;
    const int b = blockIdx.z;              // half-relative

    if (tid < BM) cb[tid] = conv_b[co0 + tid];

    f32x4 acc[4][4];
#pragma unroll
    for (int m = 0; m < 4; ++m)
#pragma unroll
        for (int n = 0; n < 4; ++n) acc[m][n] = {0.f, 0.f, 0.f, 0.f};

    const size_t ftbase = (size_t)b * FTR * C_;
    const int erow = tid >> 3;             // 0..31
    const int ecol = (tid & 7) * 8;        // 0..56

    for (int ks = 0; ks < 24; ++ks) {
        const int t = ks >> 3, kc = (ks & 7) * 64;
        __syncthreads();
#pragma unroll
        for (int ch = 0; ch < 4; ++ch) {
            const int row = ch * 32 + erow;
            gload16(&W2[(size_t)(co0 + row) * KTOT + t * 512 + kc + ecol],
                    &As[row * 64 + ecol]);
            gload16(&FT[ftbase + (size_t)(l0 + t + row) * C_ + kc + ecol],
                    &Bs[row * 64 + ecol]);
        }
        __syncthreads();
#pragma unroll
        for (int kk = 0; kk < 2; ++kk) {
            const int ko = kk * 32 + g * 8;
            bh8 af[4], bfr[4];
#pragma unroll
            for (int m = 0; m < 4; ++m)
                af[m] = *(const bh8*)&As[(wm * 64 + m * 16 + cL) * 64 + ko];
#pragma unroll
            for (int n = 0; n < 4; ++n)
                bfr[n] = *(const bh8*)&Bs[(wn * 64 + n * 16 + cL) * 64 + ko];
#pragma unroll
            for (int m = 0; m < 4; ++m)
#pragma unroll
                for (int n = 0; n < 4; ++n)
                    acc[m][n] = __builtin_amdgcn_mfma_f32_16x16x32_bf16(af[m], bfr[n],
                                                                        acc[m][n], 0, 0, 0);
        }
    }
    __syncthreads();   // all MFMA LDS reads done; safe to overwrite As/Bs

    // bias + relu -> Hs[l][co] bf16
#pragma unroll
    for (int m = 0; m < 4; ++m) {
        const int co_b = wm * 64 + m * 16 + g * 4;
        const float b0_ = cb[co_b + 0], b1_ = cb[co_b + 1];
        const float b2_ = cb[co_b + 2], b3_ = cb[co_b + 3];
#pragma unroll
        for (int n = 0; n < 4; ++n) {
            const int l = wn * 64 + n * 16 + cL;
            f32x4 v = acc[m][n];
            u32 p0 = (u32)f2bf(fmaxf(v[0] + b0_, 0.f)) |
                     ((u32)f2bf(fmaxf(v[1] + b1_, 0.f)) << 16);
            u32 p1 = (u32)f2bf(fmaxf(v[2] + b2_, 0.f)) |
                     ((u32)f2bf(fmaxf(v[3] + b3_, 0.f)) << 16);
            *(u32*)((char*)Hs + l * (HSLD * 2) + co_b * 2) = p0;
            *(u32*)((char*)Hs + l * (HSLD * 2) + co_b * 2 + 4) = p1;
        }
    }
    // stage head weights Wp[a][c]: a<7 obj, 7..20 reg, 21..31 zero
    for (int i = tid; i < 32 * 128; i += 256) {
        int a = i >> 7, c = i & 127;
        float w = (a < 7) ? obj_w[a * C_ + co0 + c]
                : (a < 21) ? reg_w[(a - 7) * C_ + co0 + c]
                           : 0.f;
        Wp[a * HSLD + c] = f2bf(w);
    }
    __syncthreads();

    // head MFMA: D[a][l] = sum_c Wp[a][c] * Hs[l][c]
    f32x4 hacc[2][2];
#pragma unroll
    for (int m = 0; m < 2; ++m)
#pragma unroll
        for (int n = 0; n < 2; ++n) hacc[m][n] = {0.f, 0.f, 0.f, 0.f};
    const int ln0 = wave * 32;
#pragma unroll
    for (int ks2 = 0; ks2 < 4; ++ks2) {
        const int ko = ks2 * 32 + g * 8;
        bh8 wa[2], hb[2];
        wa[0] = *(const bh8*)&Wp[(cL)*HSLD + ko];
        wa[1] = *(const bh8*)&Wp[(16 + cL) * HSLD + ko];
        hb[0] = *(const bh8*)&Hs[(ln0 + cL) * HSLD + ko];
        hb[1] = *(const bh8*)&Hs[(ln0 + 16 + cL) * HSLD + ko];
#pragma unroll
        for (int m = 0; m < 2; ++m)
#pragma unroll
            for (int n = 0; n < 2; ++n)
                hacc[m][n] = __builtin_amdgcn_mfma_f32_16x16x32_bf16(wa[m], hb[n],
                                                                    hacc[m][n], 0, 0, 0);
    }
    // store partials: P4[mt][bglob][a][l]
    const int bglob = b0 + b;
    float* P4base = P4 + ((size_t)(mt * B_ + bglob) * 21) * LF + l0;
#pragma unroll
    for (int m = 0; m < 2; ++m) {
        const int a0 = m * 16 + g * 4;
#pragma unroll
        for (int n = 0; n < 2; ++n) {
            const int l = ln0 + n * 16 + cL;
#pragma unroll
            for (int r = 0; r < 4; ++r) {
                const int a = a0 + r;
                if (a < 21) P4base[(size_t)a * LF + l] = hacc[m][n][r];
            }
        }
    }
}

// ---------------- reduce partials, add biases, write f32 obj/reg ----------------
__global__ void k_finalize(const float* __restrict__ P4, const float* __restrict__ obj_b,
                           const float* __restrict__ reg_b, float* __restrict__ out) {
    int gid = blockIdx.x * 256 + threadIdx.x;
    if (gid >= B_ * LF) return;
    int b = gid >> 14, l = gid & (LF - 1);
    float s[21];
#pragma unroll
    for (int a = 0; a < 21; ++a) {
        float v = 0.f;
#pragma unroll
        for (int m = 0; m < 4; ++m) v += P4[((size_t)(m * B_ + b) * 21 + a) * LF + l];
        s[a] = v;
    }
    float* op = out + OBJ_OFF + (size_t)b * (LF * 7) + (size_t)l * 7;
#pragma unroll
    for (int a = 0; a < 7; ++a) op[a] = s[a] + obj_b[a];
    float* rp = out + REG_OFF + (size_t)b * (LF * 14) + (size_t)l * 14;
#pragma unroll
    for (int o = 0; o < 14; ++o) rp[o] = s[7 + o] + reg_b[o];
}

extern "C" void kernel_launch(void* const* d_in, const int* in_sizes, int n_in,
                              void* d_out, int out_size, void* d_ws, size_t ws_size,
                              hipStream_t stream) {
    const float* feat   = (const float*)d_in[0];
    const float* conv_w = (const float*)d_in[1];
    const float* conv_b = (const float*)d_in[2];
    const float* obj_w  = (const float*)d_in[3];
    const float* obj_b  = (const float*)d_in[4];
    const float* reg_w  = (const float*)d_in[5];
    const float* reg_b  = (const float*)d_in[6];
    char* ws = (char*)d_ws;
    u16* FT   = (u16*)(ws + FT_OFF);
    float* P4 = (float*)(ws + P4_OFF);
    u16* W2   = (u16*)(ws + W2_OFF);
    float* out = (float*)d_out;

    k_cast_w<<<(C_ * KTOT + 255) / 256, 256, 0, stream>>>(conv_w, W2);
    k_anchors<<<LF / 256, 256, 0, stream>>>(out);

    for (int h = 0; h < 2; ++h) {
        const int b0 = h * 4;
        k_zero_pad<<<16, 256, 0, stream>>>(FT);
        dim3 gt(LF / 64, C_ / 32, 4);
        k_transpose<<<gt, 256, 0, stream>>>(feat, FT, b0);
        dim3 gc(LF / BN, C_ / BM, 4);
        k_conv_head<<<gc, 256, 0, stream>>>(FT, W2, conv_b, obj_w, reg_w, P4, b0);
    }
    k_finalize<<<(B_ * LF + 255) / 256, 256, 0, stream>>>(P4, obj_b, reg_b, out);
}

// Round 6
// 277.149 us; speedup vs baseline: 1.6965x; 1.2886x over previous
//
#include <hip/hip_runtime.h>
#include <hip/hip_bf16.h>
#include <stdint.h>

typedef __attribute__((ext_vector_type(8))) short bh8;
typedef __attribute__((ext_vector_type(4))) float f32x4;
typedef unsigned short u16;
typedef unsigned int u32;

#define B_    8
#define C_    512
#define LF    16384
#define KTOT  1536
#define BM    128
#define BN    128
#define LDB   72            // u16 stride of Bs rows (64 + 8 pad)
#define HSLD  136           // u16 stride of Hs/Wp rows (128 + 8 pad)

// ws layout (bytes)
#define P4_BYTES ((size_t)4 * B_ * 21 * LF * 4)      // 44,040,192
#define W2_OFF   P4_BYTES

// output chunk offsets (float32 elements)
#define OBJ_OFF  0
#define REG_OFF  917504      // 8 * 16384*7
#define ANC_OFF  2752512     // REG_OFF + 8*16384*14

__device__ __forceinline__ u16 f2bf(float f) {
    u32 u = __float_as_uint(f);
    return (u16)((u + 0x7FFFu + ((u >> 16) & 1u)) >> 16);
}

__device__ __forceinline__ void gload16(const u16* g, u16* l) {
    __builtin_amdgcn_global_load_lds(
        (const __attribute__((address_space(1))) void*)g,
        (__attribute__((address_space(3))) void*)l, 16, 0, 0);
}

// ---------------- cast conv_w -> W2[co][t*512+ci] (t-major K) ----------------
__global__ void k_cast_w(const float* __restrict__ cw, u16* __restrict__ W2) {
    int i = blockIdx.x * 256 + threadIdx.x;
    if (i >= C_ * KTOT) return;
    int co = i / KTOT, r = i % KTOT;
    int t = r >> 9, ci = r & 511;
    W2[i] = f2bf(cw[(co * C_ + ci) * 3 + t]);
}

// ---------------- anchors (float32 out) ----------------
__global__ void k_anchors(float* __restrict__ out) {
    int l = blockIdx.x * 256 + threadIdx.x;
    if (l >= LF) return;
    const float AL[7] = {1.f, 2.f, 3.f, 4.f, 5.f, 7.f, 9.f};
    float c = (float)l + 0.5f;
    float* an = out + ANC_OFF + (size_t)l * 14;
#pragma unroll
    for (int a = 0; a < 7; ++a) {
        an[a * 2 + 0] = c - 0.5f * AL[a];
        an[a * 2 + 1] = c + 0.5f * AL[a];
    }
}

// ---------------- conv GEMM (direct feat read, tap-dedup B) + fused head ----------------
// 1-D grid of 4096 blocks, XCD-swizzled; 256 threads (4 waves, 2x2)
__global__ __launch_bounds__(256, 3) void k_conv_head(
    const float* __restrict__ feat, const u16* __restrict__ W2,
    const float* __restrict__ conv_b, const float* __restrict__ obj_w,
    const float* __restrict__ reg_w, float* __restrict__ P4) {
    __shared__ __align__(16) char smem[44320];
    u16* As = (u16*)smem;                  // [128][64] linear (gload dest)      @0
    u16* Bs = (u16*)(smem + 16384);        // [130][72] padded (reg-staged)      @16384..35104
    u16* Hs = (u16*)smem;                  // [128][136] epilogue (overlap)      @0..34816
    u16* Wp = (u16*)(smem + 35104);        // [32][136]  epilogue                @35104..43808
    float* cb = (float*)(smem + 43808);    // [128]

    const int tid = threadIdx.x;
    const int lane = tid & 63, wave = tid >> 6;
    const int wm = wave >> 1, wn = wave & 1;
    const int g = lane >> 4, cL = lane & 15;

    // XCD-aware swizzle: 4096 = 8 XCDs * 512; consecutive wg share (l0,b) across mt
    const int wg = (blockIdx.x & 7) * 512 + (blockIdx.x >> 3);
    const int mt = wg & 3;
    const int l0 = ((wg >> 2) & 127) * BN;
    const int b  = wg >> 9;
    const int co0 = mt * BM;

    if (tid < BM) cb[tid] = conv_b[co0 + tid];

    f32x4 acc[4][4];
#pragma unroll
    for (int m = 0; m < 4; ++m)
#pragma unroll
        for (int n = 0; n < 4; ++n) acc[m][n] = {0.f, 0.f, 0.f, 0.f};

    const int bci = tid >> 2;              // 0..63  (B-stage ci)
    const int brp = (tid & 3) * 4;         // 0,4,8,12
    const int arow = tid >> 3;             // 0..31  (A-stage row)
    const int acol = (tid & 7) * 8;

    for (int kc = 0; kc < 8; ++kc) {
        __syncthreads();   // prior readers of As/Bs done
        // ---- stage Bs rows 1..128 (l = l0 .. l0+127), transposed from feat ----
        {
            const float* fp = feat + ((size_t)(b * C_ + kc * 64 + bci)) * LF + l0;
            u16* bw = Bs + bci;
#pragma unroll
            for (int p = 0; p < 8; ++p) {
                const int lr = p * 16 + brp;           // 0..124 (aligned)
                float4 v = *(const float4*)(fp + lr);
                const int r = lr + 1;
                bw[(r + 0) * LDB] = f2bf(v.x);
                bw[(r + 1) * LDB] = f2bf(v.y);
                bw[(r + 2) * LDB] = f2bf(v.z);
                bw[(r + 3) * LDB] = f2bf(v.w);
            }
        }
        // ---- halo rows r=0 (l0-1) and r=129 (l0+128) ----
        if (tid < 128) {
            const int ci2 = tid >> 1;
            const int rr = (tid & 1) ? 129 : 0;
            const int l = l0 + rr - 1;
            float v = (l >= 0 && l < LF)
                          ? feat[((size_t)(b * C_ + kc * 64 + ci2)) * LF + l]
                          : 0.f;
            Bs[rr * LDB + ci2] = f2bf(v);
        }
        // ---- taps ----
#pragma unroll
        for (int t = 0; t < 3; ++t) {
            if (t > 0) __syncthreads();    // As readers done
#pragma unroll
            for (int p = 0; p < 4; ++p) {
                const int row = p * 32 + arow;
                gload16(&W2[(size_t)(co0 + row) * KTOT + t * 512 + kc * 64 + acol],
                        &As[row * 64 + acol]);
            }
            __syncthreads();               // As + Bs ready
#pragma unroll
            for (int kk = 0; kk < 2; ++kk) {
                const int ko = kk * 32 + g * 8;
                bh8 af[4], bfr[4];
#pragma unroll
                for (int m = 0; m < 4; ++m)
                    af[m] = *(const bh8*)&As[(wm * 64 + m * 16 + cL) * 64 + ko];
#pragma unroll
                for (int n = 0; n < 4; ++n)
                    bfr[n] = *(const bh8*)&Bs[(wn * 64 + n * 16 + cL + t) * LDB + ko];
#pragma unroll
                for (int m = 0; m < 4; ++m)
#pragma unroll
                    for (int n = 0; n < 4; ++n)
                        acc[m][n] = __builtin_amdgcn_mfma_f32_16x16x32_bf16(
                            af[m], bfr[n], acc[m][n], 0, 0, 0);
            }
        }
    }
    __syncthreads();   // all MFMA LDS reads done; safe to overwrite As/Bs

    // bias + relu -> Hs[l][co] bf16
#pragma unroll
    for (int m = 0; m < 4; ++m) {
        const int co_b = wm * 64 + m * 16 + g * 4;
        const float b0_ = cb[co_b + 0], b1_ = cb[co_b + 1];
        const float b2_ = cb[co_b + 2], b3_ = cb[co_b + 3];
#pragma unroll
        for (int n = 0; n < 4; ++n) {
            const int l = wn * 64 + n * 16 + cL;
            f32x4 v = acc[m][n];
            u32 p0 = (u32)f2bf(fmaxf(v[0] + b0_, 0.f)) |
                     ((u32)f2bf(fmaxf(v[1] + b1_, 0.f)) << 16);
            u32 p1 = (u32)f2bf(fmaxf(v[2] + b2_, 0.f)) |
                     ((u32)f2bf(fmaxf(v[3] + b3_, 0.f)) << 16);
            *(u32*)((char*)Hs + l * (HSLD * 2) + co_b * 2) = p0;
            *(u32*)((char*)Hs + l * (HSLD * 2) + co_b * 2 + 4) = p1;
        }
    }
    // stage head weights Wp[a][c]: a<7 obj, 7..20 reg, 21..31 zero
    for (int i = tid; i < 32 * 128; i += 256) {
        int a = i >> 7, c = i & 127;
        float w = (a < 7) ? obj_w[a * C_ + co0 + c]
                : (a < 21) ? reg_w[(a - 7) * C_ + co0 + c]
                           : 0.f;
        Wp[a * HSLD + c] = f2bf(w);
    }
    __syncthreads();

    // head MFMA: D[a][l] = sum_c Wp[a][c] * Hs[l][c]
    f32x4 hacc[2][2];
#pragma unroll
    for (int m = 0; m < 2; ++m)
#pragma unroll
        for (int n = 0; n < 2; ++n) hacc[m][n] = {0.f, 0.f, 0.f, 0.f};
    const int ln0 = wave * 32;
#pragma unroll
    for (int ks2 = 0; ks2 < 4; ++ks2) {
        const int ko = ks2 * 32 + g * 8;
        bh8 wa[2], hb[2];
        wa[0] = *(const bh8*)&Wp[(cL)*HSLD + ko];
        wa[1] = *(const bh8*)&Wp[(16 + cL) * HSLD + ko];
        hb[0] = *(const bh8*)&Hs[(ln0 + cL) * HSLD + ko];
        hb[1] = *(const bh8*)&Hs[(ln0 + 16 + cL) * HSLD + ko];
#pragma unroll
        for (int m = 0; m < 2; ++m)
#pragma unroll
            for (int n = 0; n < 2; ++n)
                hacc[m][n] = __builtin_amdgcn_mfma_f32_16x16x32_bf16(wa[m], hb[n],
                                                                    hacc[m][n], 0, 0, 0);
    }
    // store partials: P4[mt][b][a][l]
    float* P4base = P4 + ((size_t)(mt * B_ + b) * 21) * LF + l0;
#pragma unroll
    for (int m = 0; m < 2; ++m) {
        const int a0 = m * 16 + g * 4;
#pragma unroll
        for (int n = 0; n < 2; ++n) {
            const int l = ln0 + n * 16 + cL;
#pragma unroll
            for (int r = 0; r < 4; ++r) {
                const int a = a0 + r;
                if (a < 21) P4base[(size_t)a * LF + l] = hacc[m][n][r];
            }
        }
    }
}

// ---------------- reduce partials, add biases, write f32 obj/reg ----------------
__global__ void k_finalize(const float* __restrict__ P4, const float* __restrict__ obj_b,
                           const float* __restrict__ reg_b, float* __restrict__ out) {
    int gid = blockIdx.x * 256 + threadIdx.x;
    if (gid >= B_ * LF) return;
    int b = gid >> 14, l = gid & (LF - 1);
    float s[21];
#pragma unroll
    for (int a = 0; a < 21; ++a) {
        float v = 0.f;
#pragma unroll
        for (int m = 0; m < 4; ++m) v += P4[((size_t)(m * B_ + b) * 21 + a) * LF + l];
        s[a] = v;
    }
    float* op = out + OBJ_OFF + (size_t)b * (LF * 7) + (size_t)l * 7;
#pragma unroll
    for (int a = 0; a < 7; ++a) op[a] = s[a] + obj_b[a];
    float* rp = out + REG_OFF + (size_t)b * (LF * 14) + (size_t)l * 14;
#pragma unroll
    for (int o = 0; o < 14; ++o) rp[o] = s[7 + o] + reg_b[o];
}

extern "C" void kernel_launch(void* const* d_in, const int* in_sizes, int n_in,
                              void* d_out, int out_size, void* d_ws, size_t ws_size,
                              hipStream_t stream) {
    const float* feat   = (const float*)d_in[0];
    const float* conv_w = (const float*)d_in[1];
    const float* conv_b = (const float*)d_in[2];
    const float* obj_w  = (const float*)d_in[3];
    const float* obj_b  = (const float*)d_in[4];
    const float* reg_w  = (const float*)d_in[5];
    const float* reg_b  = (const float*)d_in[6];
    char* ws = (char*)d_ws;
    float* P4 = (float*)ws;
    u16* W2   = (u16*)(ws + W2_OFF);
    float* out = (float*)d_out;

    k_cast_w<<<(C_ * KTOT + 255) / 256, 256, 0, stream>>>(conv_w, W2);
    k_anchors<<<LF / 256, 256, 0, stream>>>(out);
    k_conv_head<<<4096, 256, 0, stream>>>(feat, W2, conv_b, obj_w, reg_w, P4);
    k_finalize<<<(B_ * LF + 255) / 256, 256, 0, stream>>>(P4, obj_b, reg_b, out);
}